// Round 7
// baseline (36.337 us; speedup 1.0000x reference)
//
#include <hip/hip_runtime.h>
#include <hip/hip_bf16.h>
#include <math.h>

// PyramidROIAlign, three-kernel scheme:
//  K0: stream-convert P3,P4,P5 (fp32 -> bf16, RNE) into d_ws (~11MB). Halves
//      the gathered read bytes for ~90% of boxes and makes the per-XCD read
//      working set L2-resident.
//  K1: 256-bin counting sort of box indices by (level,ybin,xbin) -> perm.
//  K2: one wave per (sorted box, py) row; 64 lanes x 4 channels; levels 3-5
//      read bf16 (exact <<16 upconvert, fp32 math), level 2 reads P2 fp32.
//      XCD-chunked swizzle + nontemporal stores.
// Fp32 fallback kernel if ws_size can't hold the bf16 pyramid.

#define CCH 256
#define PH 7
#define PW 7
#define NXCD 8

typedef float nat_float4 __attribute__((ext_vector_type(4)));
typedef unsigned short nat_ushort4 __attribute__((ext_vector_type(4)));

__device__ __forceinline__ unsigned short f2bf(float f) {
    unsigned u = __float_as_uint(f);
    return (unsigned short)((u + 0x7fffu + ((u >> 16) & 1u)) >> 16);  // RNE
}
__device__ __forceinline__ float bf_lo(unsigned x) { return __uint_as_float(x << 16); }
__device__ __forceinline__ float bf_hi(unsigned x) { return __uint_as_float(x & 0xffff0000u); }

__global__ __launch_bounds__(256) void convert_kernel(
    const float* __restrict__ P3, const float* __restrict__ P4,
    const float* __restrict__ P5,
    unsigned short* __restrict__ B3, unsigned short* __restrict__ B4,
    unsigned short* __restrict__ B5,
    int n3_4, int n4_4, int n5_4)    // element counts / 4
{
    int total = n3_4 + n4_4 + n5_4;
    int stride = gridDim.x * blockDim.x;
    for (int i = blockIdx.x * blockDim.x + threadIdx.x; i < total; i += stride) {
        const float* src; unsigned short* dst; int j = i;
        if (j < n3_4) { src = P3; dst = B3; }
        else if (j - n3_4 < n4_4) { j -= n3_4; src = P4; dst = B4; }
        else { j -= n3_4 + n4_4; src = P5; dst = B5; }
        float4 v = ((const float4*)src)[j];
        nat_ushort4 o;
        o.x = f2bf(v.x); o.y = f2bf(v.y); o.z = f2bf(v.z); o.w = f2bf(v.w);
        ((nat_ushort4*)dst)[j] = o;
    }
}

__global__ __launch_bounds__(256) void sort_boxes_kernel(
    const float* __restrict__ boxes, const float* __restrict__ meta,
    int* __restrict__ perm, int* __restrict__ keys, int total_boxes)
{
    __shared__ int hist[256];
    __shared__ int scan[256];
    int tid = threadIdx.x;
    hist[tid] = 0;
    __syncthreads();

    float area  = meta[4] * meta[5];
    float scale = 224.0f / sqrtf(area);

    for (int i = tid; i < total_boxes; i += 256) {
        float y1 = boxes[i * 4 + 0], x1 = boxes[i * 4 + 1];
        float y2 = boxes[i * 4 + 2], x2 = boxes[i * 4 + 3];
        int lvl = 4 + (int)rintf(log2f(sqrtf((y2 - y1) * (x2 - x1)) / scale));
        lvl = min(max(lvl, 2), 5);
        int yb = min(7, max(0, (int)((y1 + y2) * 4.0f)));
        int xb = min(7, max(0, (int)((x1 + x2) * 4.0f)));
        int key = ((lvl - 2) << 6) | (yb << 3) | xb;
        keys[i] = key;
        atomicAdd(&hist[key], 1);
    }
    __syncthreads();

    int v = hist[tid];
    scan[tid] = v;
    __syncthreads();
    #pragma unroll
    for (int d = 1; d < 256; d <<= 1) {
        int t = (tid >= d) ? scan[tid - d] : 0;
        __syncthreads();
        scan[tid] += t;
        __syncthreads();
    }
    hist[tid] = scan[tid] - v;
    __syncthreads();

    for (int i = tid; i < total_boxes; i += 256) {
        int pos = atomicAdd(&hist[keys[i]], 1);
        perm[pos] = i;
    }
}

// shared box prologue
#define BOX_PROLOGUE                                                          \
    int nwg = gridDim.x;                                                      \
    int q = nwg / NXCD, r = nwg % NXCD;                                       \
    int xcd = blockIdx.x % NXCD;                                              \
    int off = blockIdx.x / NXCD;                                              \
    int bid = (xcd < r ? xcd * (q + 1) : r * (q + 1) + (xcd - r) * q) + off;  \
    int wid  = bid * 4 + (threadIdx.x >> 6);                                  \
    int lane = threadIdx.x & 63;                                              \
    if (wid >= total_boxes * PH) return;                                      \
    wid = __builtin_amdgcn_readfirstlane(wid);                                \
    int spos = wid / PH;                                                      \
    int py   = wid - spos * PH;                                               \
    int n    = perm[spos];                                                    \
    n = __builtin_amdgcn_readfirstlane(n);                                    \
    float y1 = boxes[n * 4 + 0];                                              \
    float x1 = boxes[n * 4 + 1];                                              \
    float y2 = boxes[n * 4 + 2];                                              \
    float x2 = boxes[n * 4 + 3];                                              \
    float area  = meta[4] * meta[5];                                          \
    float scale = 224.0f / sqrtf(area);                                       \
    float lvlf  = log2f(sqrtf((y2 - y1) * (x2 - x1)) / scale);                \
    int level = 4 + (int)rintf(lvlf);                                         \
    level = min(max(level, 2), 5);

#define INTERP_STORE(V00, V01, V10, V11)                                      \
    {                                                                         \
        nat_float4 o;                                                         \
        float top, bot;                                                       \
        top = V00.x + (V01.x - V00.x) * wx;                                   \
        bot = V10.x + (V11.x - V10.x) * wx;                                   \
        o.x = top + (bot - top) * wy;                                         \
        top = V00.y + (V01.y - V00.y) * wx;                                   \
        bot = V10.y + (V11.y - V10.y) * wx;                                   \
        o.y = top + (bot - top) * wy;                                         \
        top = V00.z + (V01.z - V00.z) * wx;                                   \
        bot = V10.z + (V11.z - V10.z) * wx;                                   \
        o.z = top + (bot - top) * wy;                                         \
        top = V00.w + (V01.w - V00.w) * wx;                                   \
        bot = V10.w + (V11.w - V10.w) * wx;                                   \
        o.w = top + (bot - top) * wy;                                         \
        __builtin_nontemporal_store(o, (nat_float4*)(optr + px * CCH));       \
    }

__global__ __launch_bounds__(256, 4) void PyramidROIAlign_bf16_kernel(
    const float* __restrict__ boxes, const float* __restrict__ meta,
    const float* __restrict__ P2,
    const unsigned short* __restrict__ B3, const unsigned short* __restrict__ B4,
    const unsigned short* __restrict__ B5,
    const int* __restrict__ perm,
    float* __restrict__ out, int total_boxes, int n_per_batch)
{
    BOX_PROLOGUE

    int b = n / n_per_batch;
    float* optr;
    int c = lane << 2;

    if (level == 2) {
        const int H = 256, W = 256;
        const float* fmap = P2 + (size_t)b * H * W * CCH;
        float ty  = (float)py / (float)(PH - 1);
        float ys  = (y1 + ty * (y2 - y1)) * (float)(H - 1);
        float y0f = fminf(fmaxf(floorf(ys), 0.0f), (float)(H - 1));
        int   y0  = (int)y0f;
        int   y1r = min(y0 + 1, H - 1);
        float wy  = ys - y0f;
        const float* row0 = fmap + (size_t)y0  * W * CCH + c;
        const float* row1 = fmap + (size_t)y1r * W * CCH + c;
        optr = out + ((size_t)n * (PH * PW) + py * PW) * CCH + c;
        #pragma unroll
        for (int px = 0; px < PW; ++px) {
            float tx  = (float)px / (float)(PW - 1);
            float xs  = (x1 + tx * (x2 - x1)) * (float)(W - 1);
            float x0f = fminf(fmaxf(floorf(xs), 0.0f), (float)(W - 1));
            int   x0  = (int)x0f;
            int   x1c = min(x0 + 1, W - 1);
            float wx  = xs - x0f;
            int o0 = x0  * CCH;
            int o1 = x1c * CCH;
            float4 v00 = *(const float4*)(row0 + o0);
            float4 v01 = *(const float4*)(row0 + o1);
            float4 v10 = *(const float4*)(row1 + o0);
            float4 v11 = *(const float4*)(row1 + o1);
            INTERP_STORE(v00, v01, v10, v11)
        }
    } else {
        const unsigned short* bmap;
        int H;
        switch (level) {
            case 3:  bmap = B3; H = 128; break;
            case 4:  bmap = B4; H = 64;  break;
            default: bmap = B5; H = 32;  break;
        }
        int W = H;
        bmap += (size_t)b * H * W * CCH;
        float ty  = (float)py / (float)(PH - 1);
        float ys  = (y1 + ty * (y2 - y1)) * (float)(H - 1);
        float y0f = fminf(fmaxf(floorf(ys), 0.0f), (float)(H - 1));
        int   y0  = (int)y0f;
        int   y1r = min(y0 + 1, H - 1);
        float wy  = ys - y0f;
        const unsigned short* br0 = bmap + (size_t)y0  * W * CCH + c;
        const unsigned short* br1 = bmap + (size_t)y1r * W * CCH + c;
        optr = out + ((size_t)n * (PH * PW) + py * PW) * CCH + c;
        #pragma unroll
        for (int px = 0; px < PW; ++px) {
            float tx  = (float)px / (float)(PW - 1);
            float xs  = (x1 + tx * (x2 - x1)) * (float)(W - 1);
            float x0f = fminf(fmaxf(floorf(xs), 0.0f), (float)(W - 1));
            int   x0  = (int)x0f;
            int   x1c = min(x0 + 1, W - 1);
            float wx  = xs - x0f;
            int o0 = x0  * CCH;
            int o1 = x1c * CCH;
            uint2 u00 = *(const uint2*)(const void*)(br0 + o0);
            uint2 u01 = *(const uint2*)(const void*)(br0 + o1);
            uint2 u10 = *(const uint2*)(const void*)(br1 + o0);
            uint2 u11 = *(const uint2*)(const void*)(br1 + o1);
            nat_float4 v00 = { bf_lo(u00.x), bf_hi(u00.x), bf_lo(u00.y), bf_hi(u00.y) };
            nat_float4 v01 = { bf_lo(u01.x), bf_hi(u01.x), bf_lo(u01.y), bf_hi(u01.y) };
            nat_float4 v10 = { bf_lo(u10.x), bf_hi(u10.x), bf_lo(u10.y), bf_hi(u10.y) };
            nat_float4 v11 = { bf_lo(u11.x), bf_hi(u11.x), bf_lo(u11.y), bf_hi(u11.y) };
            INTERP_STORE(v00, v01, v10, v11)
        }
    }
}

__global__ __launch_bounds__(256, 4) void PyramidROIAlign_fp32_kernel(
    const float* __restrict__ boxes, const float* __restrict__ meta,
    const float* __restrict__ P2, const float* __restrict__ P3,
    const float* __restrict__ P4, const float* __restrict__ P5,
    const int* __restrict__ perm,
    float* __restrict__ out, int total_boxes, int n_per_batch)
{
    BOX_PROLOGUE

    const float* fmap;
    int H;
    switch (level) {
        case 2:  fmap = P2; H = 256; break;
        case 3:  fmap = P3; H = 128; break;
        case 4:  fmap = P4; H = 64;  break;
        default: fmap = P5; H = 32;  break;
    }
    int W = H;
    int b = n / n_per_batch;
    fmap += (size_t)b * H * W * CCH;

    float ty  = (float)py / (float)(PH - 1);
    float ys  = (y1 + ty * (y2 - y1)) * (float)(H - 1);
    float y0f = fminf(fmaxf(floorf(ys), 0.0f), (float)(H - 1));
    int   y0  = (int)y0f;
    int   y1r = min(y0 + 1, H - 1);
    float wy  = ys - y0f;

    int c = lane << 2;
    const float* row0 = fmap + (size_t)y0  * W * CCH + c;
    const float* row1 = fmap + (size_t)y1r * W * CCH + c;
    float* optr = out + ((size_t)n * (PH * PW) + py * PW) * CCH + c;

    #pragma unroll
    for (int px = 0; px < PW; ++px) {
        float tx  = (float)px / (float)(PW - 1);
        float xs  = (x1 + tx * (x2 - x1)) * (float)(W - 1);
        float x0f = fminf(fmaxf(floorf(xs), 0.0f), (float)(W - 1));
        int   x0  = (int)x0f;
        int   x1c = min(x0 + 1, W - 1);
        float wx  = xs - x0f;
        int o0 = x0  * CCH;
        int o1 = x1c * CCH;
        float4 v00 = *(const float4*)(row0 + o0);
        float4 v01 = *(const float4*)(row0 + o1);
        float4 v10 = *(const float4*)(row1 + o0);
        float4 v11 = *(const float4*)(row1 + o1);
        INTERP_STORE(v00, v01, v10, v11)
    }
}

extern "C" void kernel_launch(void* const* d_in, const int* in_sizes, int n_in,
                              void* d_out, int out_size, void* d_ws, size_t ws_size,
                              hipStream_t stream) {
    const float* boxes = (const float*)d_in[0];   // [B,N,4]
    const float* meta  = (const float*)d_in[1];   // [B,93]
    const float* P2    = (const float*)d_in[2];
    const float* P3    = (const float*)d_in[3];
    const float* P4    = (const float*)d_in[4];
    const float* P5    = (const float*)d_in[5];
    float* out = (float*)d_out;

    int total_boxes = in_sizes[0] / 4;            // B*N
    int B = in_sizes[1] / 93;
    if (B < 1) B = 1;
    int n_per_batch = total_boxes / B;

    int n3 = in_sizes[3], n4 = in_sizes[4], n5 = in_sizes[5];

    int* perm = (int*)d_ws;
    int* keys = perm + total_boxes;
    size_t bfOff = (((size_t)2 * total_boxes * sizeof(int)) + 255) & ~(size_t)255;
    size_t need = bfOff + (size_t)(n3 + n4 + n5) * sizeof(unsigned short);
    bool use_bf16 = (ws_size >= need);

    unsigned short* B3 = (unsigned short*)((char*)d_ws + bfOff);
    unsigned short* B4 = B3 + n3;
    unsigned short* B5 = B4 + n4;

    sort_boxes_kernel<<<1, 256, 0, stream>>>(boxes, meta, perm, keys, total_boxes);

    long total_waves = (long)total_boxes * PH;
    int blocks = (int)((total_waves + 3) / 4);

    if (use_bf16) {
        int tot4 = (n3 + n4 + n5) / 4;
        int cblocks = min(2048, (tot4 + 255) / 256);
        convert_kernel<<<cblocks, 256, 0, stream>>>(P3, P4, P5, B3, B4, B5,
                                                    n3 / 4, n4 / 4, n5 / 4);
        PyramidROIAlign_bf16_kernel<<<blocks, 256, 0, stream>>>(
            boxes, meta, P2, B3, B4, B5, perm, out, total_boxes, n_per_batch);
    } else {
        PyramidROIAlign_fp32_kernel<<<blocks, 256, 0, stream>>>(
            boxes, meta, P2, P3, P4, P5, perm, out, total_boxes, n_per_batch);
    }
}

// Round 8
// 28.260 us; speedup vs baseline: 1.2858x; 1.2858x over previous
//
#include <hip/hip_runtime.h>
#include <hip/hip_bf16.h>
#include <math.h>

// PyramidROIAlign, two-kernel scheme (best-known config, round 6):
//  K1: 256-bin counting sort of box indices by (level, ybin, xbin) -> perm.
//      Keys computed ONCE (stored in d_ws), prefix via parallel Hillis-Steele
//      scan (8 steps).  ~1us.
//  K2: one wave per (sorted box, py) row; 64 lanes x 4 channels; XCD-chunked
//      block swizzle; nontemporal float4 output stores.
// NOTE (round 7 lesson): bf16-converting the pyramid halved read bytes but
// left the main kernel flat -> the kernel is vmem-REQUEST-bound (1KB gather
// granularity, ~73 cy/request at L3 tier), not bytes-bound. Request count is
// at the algorithmic minimum, so this structure is the practical floor.

#define CCH 256
#define PH 7
#define PW 7
#define NXCD 8

typedef float nat_float4 __attribute__((ext_vector_type(4)));

__global__ __launch_bounds__(256) void sort_boxes_kernel(
    const float* __restrict__ boxes, const float* __restrict__ meta,
    int* __restrict__ perm, int* __restrict__ keys, int total_boxes)
{
    __shared__ int hist[256];
    __shared__ int scan[256];
    int tid = threadIdx.x;
    hist[tid] = 0;
    __syncthreads();

    float area  = meta[4] * meta[5];
    float scale = 224.0f / sqrtf(area);

    for (int i = tid; i < total_boxes; i += 256) {
        float y1 = boxes[i * 4 + 0], x1 = boxes[i * 4 + 1];
        float y2 = boxes[i * 4 + 2], x2 = boxes[i * 4 + 3];
        int lvl = 4 + (int)rintf(log2f(sqrtf((y2 - y1) * (x2 - x1)) / scale));
        lvl = min(max(lvl, 2), 5);
        int yb = min(7, max(0, (int)((y1 + y2) * 4.0f)));
        int xb = min(7, max(0, (int)((x1 + x2) * 4.0f)));
        int key = ((lvl - 2) << 6) | (yb << 3) | xb;
        keys[i] = key;
        atomicAdd(&hist[key], 1);
    }
    __syncthreads();

    int v = hist[tid];
    scan[tid] = v;
    __syncthreads();
    #pragma unroll
    for (int d = 1; d < 256; d <<= 1) {
        int t = (tid >= d) ? scan[tid - d] : 0;
        __syncthreads();
        scan[tid] += t;
        __syncthreads();
    }
    hist[tid] = scan[tid] - v;   // exclusive prefix, reuse hist[] as base
    __syncthreads();

    for (int i = tid; i < total_boxes; i += 256) {
        int pos = atomicAdd(&hist[keys[i]], 1);
        perm[pos] = i;
    }
}

__global__ __launch_bounds__(256, 4) void PyramidROIAlign_kernel(
    const float* __restrict__ boxes,   // [TB,4]
    const float* __restrict__ meta,    // [B,93]
    const float* __restrict__ P2,
    const float* __restrict__ P3,
    const float* __restrict__ P4,
    const float* __restrict__ P5,
    const int*   __restrict__ perm,    // [TB] sorted box ids
    float* __restrict__ out,           // [TB,7,7,C]
    int total_boxes,
    int n_per_batch)
{
    // bijective XCD-chunk remap: each XCD gets a contiguous range of the
    // level/space-sorted box list.
    int nwg = gridDim.x;
    int q = nwg / NXCD, r = nwg % NXCD;
    int xcd = blockIdx.x % NXCD;
    int off = blockIdx.x / NXCD;
    int bid = (xcd < r ? xcd * (q + 1) : r * (q + 1) + (xcd - r) * q) + off;

    int wid  = bid * 4 + (threadIdx.x >> 6);
    int lane = threadIdx.x & 63;
    if (wid >= total_boxes * PH) return;
    wid = __builtin_amdgcn_readfirstlane(wid);

    int spos = wid / PH;           // position in sorted order
    int py   = wid - spos * PH;
    int n    = perm[spos];         // original box id (output slot)
    n = __builtin_amdgcn_readfirstlane(n);

    float y1 = boxes[n * 4 + 0];
    float x1 = boxes[n * 4 + 1];
    float y2 = boxes[n * 4 + 2];
    float x2 = boxes[n * 4 + 3];

    float area  = meta[4] * meta[5];
    float scale = 224.0f / sqrtf(area);
    float lvlf  = log2f(sqrtf((y2 - y1) * (x2 - x1)) / scale);
    int level = 4 + (int)rintf(lvlf);
    level = min(max(level, 2), 5);

    const float* fmap;
    int H;
    switch (level) {
        case 2:  fmap = P2; H = 256; break;
        case 3:  fmap = P3; H = 128; break;
        case 4:  fmap = P4; H = 64;  break;
        default: fmap = P5; H = 32;  break;
    }
    int W = H;
    int b = n / n_per_batch;
    fmap += (size_t)b * H * W * CCH;

    float ty  = (float)py / (float)(PH - 1);
    float ys  = (y1 + ty * (y2 - y1)) * (float)(H - 1);
    float y0f = fminf(fmaxf(floorf(ys), 0.0f), (float)(H - 1));
    int   y0  = (int)y0f;
    int   y1r = min(y0 + 1, H - 1);
    float wy  = ys - y0f;

    int c = lane << 2;
    const float* row0 = fmap + (size_t)y0  * W * CCH + c;
    const float* row1 = fmap + (size_t)y1r * W * CCH + c;

    float* optr = out + ((size_t)n * (PH * PW) + py * PW) * CCH + c;

    #pragma unroll
    for (int px = 0; px < PW; ++px) {
        float tx  = (float)px / (float)(PW - 1);
        float xs  = (x1 + tx * (x2 - x1)) * (float)(W - 1);
        float x0f = fminf(fmaxf(floorf(xs), 0.0f), (float)(W - 1));
        int   x0  = (int)x0f;
        int   x1c = min(x0 + 1, W - 1);
        float wx  = xs - x0f;

        int o0 = x0  * CCH;
        int o1 = x1c * CCH;
        float4 v00 = *(const float4*)(row0 + o0);
        float4 v01 = *(const float4*)(row0 + o1);
        float4 v10 = *(const float4*)(row1 + o0);
        float4 v11 = *(const float4*)(row1 + o1);

        nat_float4 o;
        float top, bot;
        top = v00.x + (v01.x - v00.x) * wx;
        bot = v10.x + (v11.x - v10.x) * wx;
        o.x = top + (bot - top) * wy;
        top = v00.y + (v01.y - v00.y) * wx;
        bot = v10.y + (v11.y - v10.y) * wx;
        o.y = top + (bot - top) * wy;
        top = v00.z + (v01.z - v00.z) * wx;
        bot = v10.z + (v11.z - v10.z) * wx;
        o.z = top + (bot - top) * wy;
        top = v00.w + (v01.w - v00.w) * wx;
        bot = v10.w + (v11.w - v10.w) * wx;
        o.w = top + (bot - top) * wy;

        __builtin_nontemporal_store(o, (nat_float4*)(optr + px * CCH));
    }
}

extern "C" void kernel_launch(void* const* d_in, const int* in_sizes, int n_in,
                              void* d_out, int out_size, void* d_ws, size_t ws_size,
                              hipStream_t stream) {
    const float* boxes = (const float*)d_in[0];   // [B,N,4]
    const float* meta  = (const float*)d_in[1];   // [B,93]
    const float* P2    = (const float*)d_in[2];
    const float* P3    = (const float*)d_in[3];
    const float* P4    = (const float*)d_in[4];
    const float* P5    = (const float*)d_in[5];
    float* out = (float*)d_out;

    int total_boxes = in_sizes[0] / 4;            // B*N
    int B = in_sizes[1] / 93;
    if (B < 1) B = 1;
    int n_per_batch = total_boxes / B;

    int* perm = (int*)d_ws;
    int* keys = perm + total_boxes;

    sort_boxes_kernel<<<1, 256, 0, stream>>>(boxes, meta, perm, keys, total_boxes);

    long total_waves = (long)total_boxes * PH;
    int blocks = (int)((total_waves + 3) / 4);

    PyramidROIAlign_kernel<<<blocks, 256, 0, stream>>>(
        boxes, meta, P2, P3, P4, P5, perm, out, total_boxes, n_per_batch);
}